// Round 1
// baseline (56594.287 us; speedup 1.0000x reference)
//
#include <hip/hip_runtime.h>
#include <math.h>

#define N_ST 512
#define N_CT 128
#define DIM  640
#define T_H  256
#define LTRI 8256   /* 128*129/2 */

// ---------------------------------------------------------------------------
// GEMM "TN": D[i,j] = alpha * sum_k A[k*lda+i] * B[k*ldb+j]  (+ Cs[i*ldc+j])
// Both operands K-major. Tile 32(M) x 64(N), KT=16, 256 threads, 2x4 micro.
// Grid = (M/32, N/64); M,N,K multiples of 32/64/16.
// ---------------------------------------------------------------------------
__global__ __launch_bounds__(256) void gemm_tn(
    const float* __restrict__ A, int lda,
    const float* __restrict__ B, int ldb,
    const float* __restrict__ Cs, int ldc,
    float* __restrict__ D, int ldd,
    int K, float alpha)
{
  __shared__ float As[16][34];
  __shared__ float Bs[16][68];
  const int tid = threadIdx.x;
  const int tx = tid & 15, ty = tid >> 4;
  const int i0 = blockIdx.x * 32, j0 = blockIdx.y * 64;
  const int iiA = tid & 31, kkA = tid >> 5;   // A: 16x32, 2/thread
  const int jjB = tid & 63, kkB = tid >> 6;   // B: 16x64, 4/thread
  float acc[2][4] = {};
  for (int k0 = 0; k0 < K; k0 += 16) {
    As[kkA][iiA]   = A[(size_t)(k0 + kkA) * lda + i0 + iiA];
    As[kkA+8][iiA] = A[(size_t)(k0 + kkA + 8) * lda + i0 + iiA];
#pragma unroll
    for (int r = 0; r < 4; r++)
      Bs[kkB + 4*r][jjB] = B[(size_t)(k0 + kkB + 4*r) * ldb + j0 + jjB];
    __syncthreads();
#pragma unroll
    for (int kk = 0; kk < 16; kk++) {
      float a0 = As[kk][ty*2+0], a1 = As[kk][ty*2+1];
      float b0 = Bs[kk][tx*4+0], b1 = Bs[kk][tx*4+1];
      float b2 = Bs[kk][tx*4+2], b3 = Bs[kk][tx*4+3];
      acc[0][0] += a0*b0; acc[0][1] += a0*b1; acc[0][2] += a0*b2; acc[0][3] += a0*b3;
      acc[1][0] += a1*b0; acc[1][1] += a1*b1; acc[1][2] += a1*b2; acc[1][3] += a1*b3;
    }
    __syncthreads();
  }
#pragma unroll
  for (int r = 0; r < 2; r++) {
    int i = i0 + ty*2 + r, j = j0 + tx*4;
    float4 o;
    o.x = alpha*acc[r][0]; o.y = alpha*acc[r][1];
    o.z = alpha*acc[r][2]; o.w = alpha*acc[r][3];
    if (Cs) {
      float4 c4 = *(const float4*)(Cs + (size_t)i*ldc + j);
      o.x += c4.x; o.y += c4.y; o.z += c4.z; o.w += c4.w;
    }
    *(float4*)(D + (size_t)i*ldd + j) = o;
  }
}

// ---------------------------------------------------------------------------
// GEMM "NN": D[i,j] = Cs[i*ldc+j] + sum_k A[i*lda+k] * B[k*ldb+j]
// ---------------------------------------------------------------------------
__global__ __launch_bounds__(256) void gemm_nn(
    const float* __restrict__ A, int lda,
    const float* __restrict__ B, int ldb,
    const float* __restrict__ Cs, int ldc,
    float* __restrict__ D, int ldd,
    int K)
{
  __shared__ float As[32][17];
  __shared__ float Bs[16][68];
  const int tid = threadIdx.x;
  const int tx = tid & 15, ty = tid >> 4;
  const int i0 = blockIdx.x * 32, j0 = blockIdx.y * 64;
  const int kkA = tid & 15, iiA = tid >> 4;   // A: 32x16, 2/thread
  const int jjB = tid & 63, kkB = tid >> 6;
  float acc[2][4] = {};
  for (int k0 = 0; k0 < K; k0 += 16) {
    As[iiA][kkA]     = A[(size_t)(i0 + iiA) * lda + k0 + kkA];
    As[iiA+16][kkA]  = A[(size_t)(i0 + iiA + 16) * lda + k0 + kkA];
#pragma unroll
    for (int r = 0; r < 4; r++)
      Bs[kkB + 4*r][jjB] = B[(size_t)(k0 + kkB + 4*r) * ldb + j0 + jjB];
    __syncthreads();
#pragma unroll
    for (int kk = 0; kk < 16; kk++) {
      float a0 = As[ty*2+0][kk], a1 = As[ty*2+1][kk];
      float b0 = Bs[kk][tx*4+0], b1 = Bs[kk][tx*4+1];
      float b2 = Bs[kk][tx*4+2], b3 = Bs[kk][tx*4+3];
      acc[0][0] += a0*b0; acc[0][1] += a0*b1; acc[0][2] += a0*b2; acc[0][3] += a0*b3;
      acc[1][0] += a1*b0; acc[1][1] += a1*b1; acc[1][2] += a1*b2; acc[1][3] += a1*b3;
    }
    __syncthreads();
  }
#pragma unroll
  for (int r = 0; r < 2; r++) {
    int i = i0 + ty*2 + r, j = j0 + tx*4;
    float4 c4 = *(const float4*)(Cs + (size_t)i*ldc + j);
    float4 o;
    o.x = c4.x + acc[r][0]; o.y = c4.y + acc[r][1];
    o.z = c4.z + acc[r][2]; o.w = c4.w + acc[r][3];
    *(float4*)(D + (size_t)i*ldd + j) = o;
  }
}

// ---------------------------------------------------------------------------
// Combo kernel (3 blocks x 1024 threads):
//  block 0: Cholesky of Quu (packed lower in LDS) -> Lout (packed), invd
//  block 1: q = c + FV@f + F^T@v
//  block 2: Vf = V@f ; fv = f.v
// ---------------------------------------------------------------------------
__global__ __launch_bounds__(1024) void combo_kernel(
    const float* __restrict__ Qm,
    const float* __restrict__ FV,
    const float* __restrict__ F,
    const float* __restrict__ f,
    const float* __restrict__ cvec,
    const float* __restrict__ vin,
    const float* __restrict__ Vin, int ldV,
    float* __restrict__ qv,
    float* __restrict__ Vf,
    float* __restrict__ fv,
    float* __restrict__ Lout,
    float* __restrict__ invd)
{
  __shared__ float Sp[LTRI];
  __shared__ float dinv[128];
  __shared__ float red[1024];
  const int tid = threadIdx.x;
  const int b = blockIdx.x;

  if (b == 0) {
    // ---- load Quu lower triangle (packed) ----
    for (int idx = tid; idx < LTRI; idx += 1024) {
      int r = (int)((sqrtf(8.0f*idx + 1.0f) - 1.0f) * 0.5f);
      while ((r+1)*(r+2)/2 <= idx) r++;
      while (r*(r+1)/2 > idx) r--;
      int c = idx - r*(r+1)/2;
      Sp[idx] = Qm[(size_t)(N_ST + r)*DIM + N_ST + c];
    }
    __syncthreads();

    for (int p = 0; p < 128; p += 16) {
      // ---- 1) 16x16 diagonal factor, wave 0, shuffles only ----
      if (tid < 64) {
        const int t = tid;
        const int toff = (p + t)*(p + t + 1)/2;  // row p+t packed offset (valid for t<16)
        float a[16];
#pragma unroll
        for (int c2 = 0; c2 < 16; c2++)
          a[c2] = (t < 16 && c2 <= t) ? Sp[toff + p + c2] : 0.0f;
        float Lr[16];
        float myinv = 0.0f;
#pragma unroll
        for (int j = 0; j < 16; j++) {
          float dj  = __shfl(a[j], j);
          float sq  = sqrtf(dj);
          float inv = 1.0f / sq;
          float Ltj = (t == j) ? sq : a[j] * inv;
#pragma unroll
          for (int jp = j + 1; jp < 16; jp++) {
            float Lpj = __shfl(Ltj, jp);
            a[jp] -= Ltj * Lpj;
          }
          Lr[j] = Ltj;
          if (t == j) myinv = inv;
        }
        if (t < 16) {
#pragma unroll
          for (int j = 0; j < 16; j++)
            if (j <= t) Sp[toff + p + j] = Lr[j];
          dinv[p + t] = myinv;
        }
      }
      __syncthreads();

      // ---- 2) panel solve, rows p+16..127 (one thread per row) ----
      {
        int r = p + 16 + tid;
        if (r < 128) {
          const int roff = r*(r+1)/2;
          float Lrow[16];
#pragma unroll
          for (int jj = 0; jj < 16; jj++) {
            float accv = Sp[roff + p + jj];
            const int doff = (p + jj)*(p + jj + 1)/2;
#pragma unroll
            for (int t2 = 0; t2 < 16; t2++)
              if (t2 < jj) accv -= Lrow[t2] * Sp[doff + p + t2];
            Lrow[jj] = accv * dinv[p + jj];
          }
#pragma unroll
          for (int jj = 0; jj < 16; jj++) Sp[roff + p + jj] = Lrow[jj];
        }
      }
      __syncthreads();

      // ---- 3) trailing update (lower triangle, 4x4 blocks) ----
      {
        int nR = 112 - p;
        if (nR > 0) {
          int nq = nR >> 2;
          int pairs = nq * (nq + 1) / 2;
          for (int e = tid; e < pairs; e += 1024) {
            int ri = (int)((sqrtf(8.0f*e + 1.0f) - 1.0f) * 0.5f);
            while ((ri+1)*(ri+2)/2 <= e) ri++;
            while (ri*(ri+1)/2 > e) ri--;
            int ci = e - ri*(ri+1)/2;
            int r0 = p + 16 + ri*4;
            int c0 = p + 16 + ci*4;
            bool dg = (ri == ci);
            int ro[4], co[4];
#pragma unroll
            for (int i2 = 0; i2 < 4; i2++) ro[i2] = (r0+i2)*(r0+i2+1)/2;
#pragma unroll
            for (int j2 = 0; j2 < 4; j2++) co[j2] = (c0+j2)*(c0+j2+1)/2;
            float acc[4][4];
#pragma unroll
            for (int i2 = 0; i2 < 4; i2++)
#pragma unroll
              for (int j2 = 0; j2 < 4; j2++)
                acc[i2][j2] = (!dg || (c0+j2) <= (r0+i2)) ? Sp[ro[i2] + c0 + j2] : 0.0f;
#pragma unroll
            for (int t2 = 0; t2 < 16; t2++) {
              float rv[4], cv2[4];
#pragma unroll
              for (int i2 = 0; i2 < 4; i2++) rv[i2]  = Sp[ro[i2] + p + t2];
#pragma unroll
              for (int j2 = 0; j2 < 4; j2++) cv2[j2] = Sp[co[j2] + p + t2];
#pragma unroll
              for (int i2 = 0; i2 < 4; i2++)
#pragma unroll
                for (int j2 = 0; j2 < 4; j2++)
                  acc[i2][j2] -= rv[i2] * cv2[j2];
            }
#pragma unroll
            for (int i2 = 0; i2 < 4; i2++)
#pragma unroll
              for (int j2 = 0; j2 < 4; j2++)
                if (!dg || (c0+j2) <= (r0+i2)) Sp[ro[i2] + c0 + j2] = acc[i2][j2];
          }
        }
      }
      __syncthreads();
    }

    // ---- write out packed L and invd ----
    for (int idx = tid; idx < LTRI; idx += 1024) Lout[idx] = Sp[idx];
    if (tid < 128) invd[tid] = dinv[tid];

  } else if (b == 1) {
    // q = c + FV@f + F^T@v
    if (tid < DIM) {
      float acc = cvec[tid];
      const float4* fr = (const float4*)(FV + (size_t)tid * N_ST);
      const float4* f4 = (const float4*)f;
      float a4 = 0.0f;
      for (int kk = 0; kk < N_ST/4; kk++) {
        float4 x = fr[kk], y = f4[kk];
        a4 += x.x*y.x + x.y*y.y + x.z*y.z + x.w*y.w;
      }
      float a2 = 0.0f;
      for (int k = 0; k < N_ST; k++)
        a2 += F[(size_t)k*DIM + tid] * vin[k];
      qv[tid] = acc + a4 + a2;
    }
  } else {
    // Vf = V@f ; fv = f.v
    if (tid < N_ST) {
      const float4* vr = (const float4*)(Vin + (size_t)tid * ldV);
      const float4* f4 = (const float4*)f;
      float a4 = 0.0f;
      for (int kk = 0; kk < N_ST/4; kk++) {
        float4 x = vr[kk], y = f4[kk];
        a4 += x.x*y.x + x.y*y.y + x.z*y.z + x.w*y.w;
      }
      Vf[tid] = a4;
    }
    float pv = (tid < N_ST) ? f[tid] * vin[tid] : 0.0f;
    red[tid] = pv;
    __syncthreads();
    for (int s2 = 512; s2 > 0; s2 >>= 1) {
      if (tid < s2) red[tid] += red[tid + s2];
      __syncthreads();
    }
    if (tid == 0) *fv = red[0];
  }
}

// ---------------------------------------------------------------------------
// TRSM: per column j (0..511 = Qux cols, 512 = qu):
//   forward  L w = b      -> W (and wv for qu col)
//   backward L^T y = w    -> K = -y (and k = -y for qu col)
// One wave per column; L packed lower in LDS.
// ---------------------------------------------------------------------------
__global__ __launch_bounds__(256) void trsm_kernel(
    const float* __restrict__ Lw,
    const float* __restrict__ invd,
    const float* __restrict__ Qm,
    const float* __restrict__ qv,
    float* __restrict__ W,
    float* __restrict__ wv,
    float* __restrict__ kv,
    float* __restrict__ outK,
    float* __restrict__ outks)
{
  __shared__ float Lp[LTRI];
  __shared__ float di[128];
  const int tid = threadIdx.x;
  for (int idx = tid; idx < LTRI; idx += 256) Lp[idx] = Lw[idx];
  if (tid < 128) di[tid] = invd[tid];
  __syncthreads();

  const int wvid = tid >> 6, lane = tid & 63;
  const int j = blockIdx.x * 4 + wvid;
  if (j > N_ST) return;

  float b0, b1;
  if (j < N_ST) {
    b0 = Qm[(size_t)(N_ST + lane)*DIM + j];
    b1 = Qm[(size_t)(N_ST + 64 + lane)*DIM + j];
  } else {
    b0 = qv[N_ST + lane];
    b1 = qv[N_ST + 64 + lane];
  }

  // forward solve
  float x0 = 0.0f, x1 = 0.0f;
  int uoff = 0;
  for (int u = 0; u < 128; u++) {
    float s = Lp[uoff + lane]*x0 + Lp[uoff + 64 + lane]*x1;
#pragma unroll
    for (int off = 32; off > 0; off >>= 1) s += __shfl_xor(s, off);
    float bu = (u < 64) ? __shfl(b0, u) : __shfl(b1, u - 64);
    float wu = (bu - s) * di[u];
    if (u < 64) { if (lane == u)      x0 = wu; }
    else        { if (lane == u - 64) x1 = wu; }
    uoff += u + 1;
  }
  if (j < N_ST) {
    W[(size_t)lane*N_ST + j]        = x0;
    W[(size_t)(64 + lane)*N_ST + j] = x1;
  } else {
    wv[lane] = x0; wv[64 + lane] = x1;
  }

  // backward solve
  const int toff0 = lane*(lane + 1)/2;
  const int toff1 = (64 + lane)*(65 + lane)/2;
  float y0 = 0.0f, y1 = 0.0f;
  for (int u = 127; u >= 0; u--) {
    float s = Lp[toff0 + u]*y0 + Lp[toff1 + u]*y1;
#pragma unroll
    for (int off = 32; off > 0; off >>= 1) s += __shfl_xor(s, off);
    float wu2 = (u < 64) ? __shfl(x0, u) : __shfl(x1, u - 64);
    float yu = (wu2 - s) * di[u];
    if (u < 64) { if (lane == u)      y0 = yu; }
    else        { if (lane == u - 64) y1 = yu; }
  }
  if (j < N_ST) {
    outK[(size_t)lane*N_ST + j]        = -y0;
    outK[(size_t)(64 + lane)*N_ST + j] = -y1;
  } else {
    kv[lane] = -y0; kv[64 + lane] = -y1;
    outks[lane] = -y0; outks[64 + lane] = -y1;
  }
}

// ---------------------------------------------------------------------------
// Finish: blocks 0..127: Vn = Qxx - W^T W (32x64 tiles) -> outV
//         blocks 128..135: vn = qx - W^T w -> outv
//         block 136: const update -> outc / wsconst
// ---------------------------------------------------------------------------
__global__ __launch_bounds__(256) void finish_kernel(
    const float* __restrict__ Qm,
    const float* __restrict__ qv,
    const float* __restrict__ W,
    const float* __restrict__ wv,
    const float* __restrict__ kv,
    const float* __restrict__ Vf,
    const float* __restrict__ fv,
    const float* __restrict__ f,
    const float* __restrict__ constp,
    float* __restrict__ outV,
    float* __restrict__ outv,
    float* __restrict__ outc,
    float* __restrict__ wsconst)
{
  const int b = blockIdx.x, tid = threadIdx.x;
  if (b < 128) {
    __shared__ float As[16][34];
    __shared__ float Bs[16][68];
    const int tx = tid & 15, ty = tid >> 4;
    const int i0 = (b >> 3) * 32, j0 = (b & 7) * 64;
    const int iiA = tid & 31, kkA = tid >> 5;
    const int jjB = tid & 63, kkB = tid >> 6;
    float acc[2][4] = {};
    for (int k0 = 0; k0 < N_CT; k0 += 16) {
      As[kkA][iiA]   = W[(size_t)(k0 + kkA)*N_ST + i0 + iiA];
      As[kkA+8][iiA] = W[(size_t)(k0 + kkA + 8)*N_ST + i0 + iiA];
#pragma unroll
      for (int r = 0; r < 4; r++)
        Bs[kkB + 4*r][jjB] = W[(size_t)(k0 + kkB + 4*r)*N_ST + j0 + jjB];
      __syncthreads();
#pragma unroll
      for (int kk = 0; kk < 16; kk++) {
        float a0 = As[kk][ty*2+0], a1 = As[kk][ty*2+1];
        float b0v = Bs[kk][tx*4+0], b1v = Bs[kk][tx*4+1];
        float b2v = Bs[kk][tx*4+2], b3v = Bs[kk][tx*4+3];
        acc[0][0] += a0*b0v; acc[0][1] += a0*b1v; acc[0][2] += a0*b2v; acc[0][3] += a0*b3v;
        acc[1][0] += a1*b0v; acc[1][1] += a1*b1v; acc[1][2] += a1*b2v; acc[1][3] += a1*b3v;
      }
      __syncthreads();
    }
#pragma unroll
    for (int r = 0; r < 2; r++) {
      int i = i0 + ty*2 + r, j = j0 + tx*4;
      float4 qx = *(const float4*)(Qm + (size_t)i*DIM + j);
      float4 o;
      o.x = qx.x - acc[r][0]; o.y = qx.y - acc[r][1];
      o.z = qx.z - acc[r][2]; o.w = qx.w - acc[r][3];
      *(float4*)(outV + (size_t)i*N_ST + j) = o;
    }
  } else if (b < 136) {
    if (tid < 64) {
      int i = (b - 128)*64 + tid;
      float acc = 0.0f;
      for (int u = 0; u < N_CT; u++) acc += W[(size_t)u*N_ST + i] * wv[u];
      outv[i] = qv[i] - acc;
    }
  } else {
    __shared__ float red[256];
    float pv = 0.0f;
    if (tid < 128) {
      float qk = 0.0f;
      for (int u = 0; u < 128; u++)
        qk += Qm[(size_t)(N_ST + tid)*DIM + N_ST + u] * kv[u];
      pv = kv[tid] * (0.5f*qk + qv[N_ST + tid]);
      float fa = 0.0f;
#pragma unroll
      for (int r = 0; r < 4; r++) { int jj = tid*4 + r; fa += f[jj] * Vf[jj]; }
      pv += 0.5f * fa;
    }
    red[tid] = pv;
    __syncthreads();
    for (int s2 = 128; s2 > 0; s2 >>= 1) {
      if (tid < s2) red[tid] += red[tid + s2];
      __syncthreads();
    }
    if (tid == 0) {
      float cn = constp[0] + red[0] + fv[0];
      outc[0] = cn;
      wsconst[0] = cn;
    }
  }
}

// ---------------------------------------------------------------------------
extern "C" void kernel_launch(void* const* d_in, const int* in_sizes, int n_in,
                              void* d_out, int out_size, void* d_ws, size_t ws_size,
                              hipStream_t stream)
{
  (void)in_sizes; (void)n_in; (void)out_size; (void)ws_size;
  const float* F  = (const float*)d_in[0];   // (512, 640)
  const float* f  = (const float*)d_in[1];   // (512,)
  const float* Cm = (const float*)d_in[2];   // (640, 640)
  const float* cv = (const float*)d_in[3];   // (640,)

  float* out   = (float*)d_out;
  float* outK  = out;                                        // T x 128 x 512
  float* outks = outK  + (size_t)T_H * N_CT * N_ST;          // T x 128
  float* outVs = outks + (size_t)T_H * N_CT;                 // T x 512 x 512
  float* outvs = outVs + (size_t)T_H * N_ST * N_ST;          // T x 512
  float* outcs = outvs + (size_t)T_H * N_ST;                 // T

  float* ws   = (float*)d_ws;
  float* FV   = ws;                          // 640*512
  float* Qm   = FV   + (size_t)DIM * N_ST;   // 640*640
  float* qv   = Qm   + (size_t)DIM * DIM;    // 640
  float* Lw   = qv   + DIM;                  // packed lower 8256
  float* invd = Lw   + LTRI;                 // 128
  float* W    = invd + N_CT;                 // 128*512
  float* wv   = W    + (size_t)N_CT * N_ST;  // 128
  float* kv   = wv   + N_CT;                 // 128
  float* Vf   = kv   + N_CT;                 // 512
  float* fv   = Vf   + N_ST;                 // 1
  float* cst  = fv   + 1;                    // 1

  hipMemsetAsync(cst, 0, sizeof(float), stream);

  for (int s = 0; s < T_H; s++) {
    const float* Vin; int ldV; const float* vin;
    if (s == 0) { Vin = Cm; ldV = DIM; vin = cv; }
    else {
      Vin = outVs + (size_t)(T_H - s) * N_ST * N_ST; ldV = N_ST;
      vin = outvs + (size_t)(T_H - s) * N_ST;
    }
    const size_t slot = (size_t)(T_H - 1 - s);

    // FV = F^T @ V   (640x512, K=512)
    dim3 g1(DIM/32, N_ST/64);
    gemm_tn<<<g1, 256, 0, stream>>>(F, DIM, Vin, ldV, nullptr, 0, FV, N_ST,
                                    N_ST, 1.0f);
    // Q = C + FV @ F  (640x640, K=512)
    dim3 g2(DIM/32, DIM/64);
    gemm_nn<<<g2, 256, 0, stream>>>(FV, N_ST, F, DIM, Cm, DIM, Qm, DIM, N_ST);
    // Cholesky(Quu) + q + Vf + fv
    combo_kernel<<<3, 1024, 0, stream>>>(Qm, FV, F, f, cv, vin, Vin, ldV,
                                         qv, Vf, fv, Lw, invd);
    // W, w, K, k
    trsm_kernel<<<129, 256, 0, stream>>>(Lw, invd, Qm, qv, W, wv, kv,
                                         outK + slot * N_CT * N_ST,
                                         outks + slot * N_CT);
    // Vn, vn, const
    finish_kernel<<<137, 256, 0, stream>>>(Qm, qv, W, wv, kv, Vf, fv, f, cst,
                                           outVs + slot * N_ST * N_ST,
                                           outvs + slot * N_ST,
                                           outcs + slot, cst);
  }
}

// Round 2
// 50050.287 us; speedup vs baseline: 1.1307x; 1.1307x over previous
//
#include <hip/hip_runtime.h>
#include <math.h>

#define N_ST 512
#define N_CT 128
#define DIM  640
#define T_H  256
#define LTRI 8256   /* 128*129/2 */

typedef __attribute__((ext_vector_type(8))) short bf16x8;
typedef __attribute__((ext_vector_type(4))) float f32x4;

__device__ __forceinline__ ushort f2bf(float x) {
  unsigned u = __float_as_uint(x);
  unsigned r = (u + 0x7fffu + ((u >> 16) & 1u)) >> 16;
  return (ushort)r;
}
__device__ __forceinline__ float bf2f(ushort h) {
  return __uint_as_float(((unsigned)h) << 16);
}

// ---------------------------------------------------------------------------
// Split-bf16 MFMA GEMM, "NT" form: D[i,j] = beta * sum_k Aarr[i,k]*Barr[j,k]
// (+ Cs[i*ldc+j]).  A/B given as hi/lo bf16 pairs, k-contiguous rows.
// Tile 64x64, 4 waves (2x2), each wave 32x32 (2x2 of 16x16x32 MFMA).
// K multiple of 64. Optionally writes bf16 split of D (Dh/Dl, same ldd).
// ---------------------------------------------------------------------------
__global__ __launch_bounds__(256) void gemm_nt_mfma(
    const ushort* __restrict__ Ah, const ushort* __restrict__ Al, int lda,
    const ushort* __restrict__ Bh, const ushort* __restrict__ Bl, int ldb,
    const float* __restrict__ Cs, int ldc, float beta,
    float* __restrict__ D, int ldd,
    ushort* __restrict__ Dh, ushort* __restrict__ Dl,
    int K)
{
  // rows padded to 72 ushorts (144B, 16B-aligned, 2-way-free banks)
  __shared__ ushort As_h[64*72], As_l[64*72], Bs_h[64*72], Bs_l[64*72];
  const int tid = threadIdx.x;
  const int i0 = blockIdx.x * 64, j0 = blockIdx.y * 64;
  const int wid = tid >> 6, lane = tid & 63;
  const int wm = (wid & 1) * 32, wn = (wid >> 1) * 32;
  const int fr = lane & 15, fq = lane >> 4;

  f32x4 acc[2][2];
#pragma unroll
  for (int a = 0; a < 2; a++)
#pragma unroll
    for (int b = 0; b < 2; b++) acc[a][b] = (f32x4){0.f, 0.f, 0.f, 0.f};

  for (int k0 = 0; k0 < K; k0 += 64) {
#pragma unroll
    for (int h = 0; h < 2; h++) {
      int c = tid + h * 256;             // 512 chunks of 16B per array
      int row = c >> 3, col = (c & 7) << 3;
      *(uint4*)&As_h[row*72 + col] = *(const uint4*)&Ah[(size_t)(i0+row)*lda + k0 + col];
      *(uint4*)&As_l[row*72 + col] = *(const uint4*)&Al[(size_t)(i0+row)*lda + k0 + col];
      *(uint4*)&Bs_h[row*72 + col] = *(const uint4*)&Bh[(size_t)(j0+row)*ldb + k0 + col];
      *(uint4*)&Bs_l[row*72 + col] = *(const uint4*)&Bl[(size_t)(j0+row)*ldb + k0 + col];
    }
    __syncthreads();
#pragma unroll
    for (int kc = 0; kc < 64; kc += 32) {
      bf16x8 ah[2], al[2], bh[2], bl[2];
#pragma unroll
      for (int t = 0; t < 2; t++) {
        ah[t] = *(bf16x8*)&As_h[(wm + t*16 + fr)*72 + kc + fq*8];
        al[t] = *(bf16x8*)&As_l[(wm + t*16 + fr)*72 + kc + fq*8];
        bh[t] = *(bf16x8*)&Bs_h[(wn + t*16 + fr)*72 + kc + fq*8];
        bl[t] = *(bf16x8*)&Bs_l[(wn + t*16 + fr)*72 + kc + fq*8];
      }
#pragma unroll
      for (int tm = 0; tm < 2; tm++)
#pragma unroll
        for (int tn = 0; tn < 2; tn++) {
          acc[tm][tn] = __builtin_amdgcn_mfma_f32_16x16x32_bf16(ah[tm], bh[tn], acc[tm][tn], 0, 0, 0);
          acc[tm][tn] = __builtin_amdgcn_mfma_f32_16x16x32_bf16(ah[tm], bl[tn], acc[tm][tn], 0, 0, 0);
          acc[tm][tn] = __builtin_amdgcn_mfma_f32_16x16x32_bf16(al[tm], bh[tn], acc[tm][tn], 0, 0, 0);
        }
    }
    __syncthreads();
  }

#pragma unroll
  for (int tm = 0; tm < 2; tm++)
#pragma unroll
    for (int tn = 0; tn < 2; tn++)
#pragma unroll
      for (int r = 0; r < 4; r++) {
        int i = i0 + wm + tm*16 + fq*4 + r;
        int j = j0 + wn + tn*16 + fr;
        float v = beta * acc[tm][tn][r];
        if (Cs) v += Cs[(size_t)i*ldc + j];
        D[(size_t)i*ldd + j] = v;
        if (Dh) {
          ushort h = f2bf(v);
          Dh[(size_t)i*ldd + j] = h;
          Dl[(size_t)i*ldd + j] = f2bf(v - bf2f(h));
        }
      }
}

// ---------------------------------------------------------------------------
// FT[i][k] = F[k][i] as bf16 hi/lo (640x512).  Once per launch.
// ---------------------------------------------------------------------------
__global__ __launch_bounds__(256) void convert_FT(
    const float* __restrict__ F, ushort* __restrict__ FTh, ushort* __restrict__ FTl)
{
  __shared__ float tile[32][33];
  const int bi = blockIdx.x, bk = blockIdx.y;
  const int tx = threadIdx.x & 31, ty = threadIdx.x >> 5;
#pragma unroll
  for (int r = 0; r < 4; r++)
    tile[ty + r*8][tx] = F[(size_t)(bk*32 + ty + r*8)*DIM + bi*32 + tx];
  __syncthreads();
#pragma unroll
  for (int r = 0; r < 4; r++) {
    float v = tile[tx][ty + r*8];
    ushort h = f2bf(v);
    size_t o = (size_t)(bi*32 + ty + r*8)*N_ST + bk*32 + tx;
    FTh[o] = h;
    FTl[o] = f2bf(v - bf2f(h));
  }
}

// V0 split from Cm[:512,:512] (ld 640). Once per launch.
__global__ __launch_bounds__(256) void convert_V0(
    const float* __restrict__ Cm, ushort* __restrict__ Vh, ushort* __restrict__ Vl)
{
  int idx = blockIdx.x * 256 + threadIdx.x;
  int i = idx >> 9, j = idx & 511;
  float v = Cm[(size_t)i*DIM + j];
  ushort h = f2bf(v);
  Vh[(size_t)i*N_ST + j] = h;
  Vl[(size_t)i*N_ST + j] = f2bf(v - bf2f(h));
}

// ---------------------------------------------------------------------------
// Combo kernel (3 blocks x 1024 threads):
//  block 0: Cholesky of Quu (packed lower in LDS) -> Lout (packed), invd
//  block 1: q = c + FV@f + F^T@v
//  block 2: Vf = V@f ; fv = f.v
// ---------------------------------------------------------------------------
__global__ __launch_bounds__(1024) void combo_kernel(
    const float* __restrict__ Qm,
    const float* __restrict__ FV,
    const float* __restrict__ F,
    const float* __restrict__ f,
    const float* __restrict__ cvec,
    const float* __restrict__ vin,
    const float* __restrict__ Vin, int ldV,
    float* __restrict__ qv,
    float* __restrict__ Vf,
    float* __restrict__ fv,
    float* __restrict__ Lout,
    float* __restrict__ invd)
{
  __shared__ float Sp[LTRI];
  __shared__ float dinv[128];
  __shared__ float red[1024];
  const int tid = threadIdx.x;
  const int b = blockIdx.x;

  if (b == 0) {
    for (int idx = tid; idx < LTRI; idx += 1024) {
      int r = (int)((sqrtf(8.0f*idx + 1.0f) - 1.0f) * 0.5f);
      while ((r+1)*(r+2)/2 <= idx) r++;
      while (r*(r+1)/2 > idx) r--;
      int c = idx - r*(r+1)/2;
      Sp[idx] = Qm[(size_t)(N_ST + r)*DIM + N_ST + c];
    }
    __syncthreads();

    for (int p = 0; p < 128; p += 16) {
      if (tid < 64) {
        const int t = tid;
        const int toff = (p + t)*(p + t + 1)/2;
        float a[16];
#pragma unroll
        for (int c2 = 0; c2 < 16; c2++)
          a[c2] = (t < 16 && c2 <= t) ? Sp[toff + p + c2] : 0.0f;
        float Lr[16];
        float myinv = 0.0f;
#pragma unroll
        for (int j = 0; j < 16; j++) {
          float dj  = __shfl(a[j], j);
          float sq  = sqrtf(dj);
          float inv = 1.0f / sq;
          float Ltj = (t == j) ? sq : a[j] * inv;
#pragma unroll
          for (int jp = j + 1; jp < 16; jp++) {
            float Lpj = __shfl(Ltj, jp);
            a[jp] -= Ltj * Lpj;
          }
          Lr[j] = Ltj;
          if (t == j) myinv = inv;
        }
        if (t < 16) {
#pragma unroll
          for (int j = 0; j < 16; j++)
            if (j <= t) Sp[toff + p + j] = Lr[j];
          dinv[p + t] = myinv;
        }
      }
      __syncthreads();

      {
        int r = p + 16 + tid;
        if (r < 128) {
          const int roff = r*(r+1)/2;
          float Lrow[16];
#pragma unroll
          for (int jj = 0; jj < 16; jj++) {
            float accv = Sp[roff + p + jj];
            const int doff = (p + jj)*(p + jj + 1)/2;
#pragma unroll
            for (int t2 = 0; t2 < 16; t2++)
              if (t2 < jj) accv -= Lrow[t2] * Sp[doff + p + t2];
            Lrow[jj] = accv * dinv[p + jj];
          }
#pragma unroll
          for (int jj = 0; jj < 16; jj++) Sp[roff + p + jj] = Lrow[jj];
        }
      }
      __syncthreads();

      {
        int nR = 112 - p;
        if (nR > 0) {
          int nq = nR >> 2;
          int pairs = nq * (nq + 1) / 2;
          for (int e = tid; e < pairs; e += 1024) {
            int ri = (int)((sqrtf(8.0f*e + 1.0f) - 1.0f) * 0.5f);
            while ((ri+1)*(ri+2)/2 <= e) ri++;
            while (ri*(ri+1)/2 > e) ri--;
            int ci = e - ri*(ri+1)/2;
            int r0 = p + 16 + ri*4;
            int c0 = p + 16 + ci*4;
            bool dg = (ri == ci);
            int ro[4], co[4];
#pragma unroll
            for (int i2 = 0; i2 < 4; i2++) ro[i2] = (r0+i2)*(r0+i2+1)/2;
#pragma unroll
            for (int j2 = 0; j2 < 4; j2++) co[j2] = (c0+j2)*(c0+j2+1)/2;
            float acc[4][4];
#pragma unroll
            for (int i2 = 0; i2 < 4; i2++)
#pragma unroll
              for (int j2 = 0; j2 < 4; j2++)
                acc[i2][j2] = (!dg || (c0+j2) <= (r0+i2)) ? Sp[ro[i2] + c0 + j2] : 0.0f;
#pragma unroll
            for (int t2 = 0; t2 < 16; t2++) {
              float rv[4], cv2[4];
#pragma unroll
              for (int i2 = 0; i2 < 4; i2++) rv[i2]  = Sp[ro[i2] + p + t2];
#pragma unroll
              for (int j2 = 0; j2 < 4; j2++) cv2[j2] = Sp[co[j2] + p + t2];
#pragma unroll
              for (int i2 = 0; i2 < 4; i2++)
#pragma unroll
                for (int j2 = 0; j2 < 4; j2++)
                  acc[i2][j2] -= rv[i2] * cv2[j2];
            }
#pragma unroll
            for (int i2 = 0; i2 < 4; i2++)
#pragma unroll
              for (int j2 = 0; j2 < 4; j2++)
                if (!dg || (c0+j2) <= (r0+i2)) Sp[ro[i2] + c0 + j2] = acc[i2][j2];
          }
        }
      }
      __syncthreads();
    }

    for (int idx = tid; idx < LTRI; idx += 1024) Lout[idx] = Sp[idx];
    if (tid < 128) invd[tid] = dinv[tid];

  } else if (b == 1) {
    if (tid < DIM) {
      float acc = cvec[tid];
      const float4* fr = (const float4*)(FV + (size_t)tid * N_ST);
      const float4* f4 = (const float4*)f;
      float a4 = 0.0f;
      for (int kk = 0; kk < N_ST/4; kk++) {
        float4 x = fr[kk], y = f4[kk];
        a4 += x.x*y.x + x.y*y.y + x.z*y.z + x.w*y.w;
      }
      float a2 = 0.0f;
      for (int k = 0; k < N_ST; k++)
        a2 += F[(size_t)k*DIM + tid] * vin[k];
      qv[tid] = acc + a4 + a2;
    }
  } else {
    if (tid < N_ST) {
      const float4* vr = (const float4*)(Vin + (size_t)tid * ldV);
      const float4* f4 = (const float4*)f;
      float a4 = 0.0f;
      for (int kk = 0; kk < N_ST/4; kk++) {
        float4 x = vr[kk], y = f4[kk];
        a4 += x.x*y.x + x.y*y.y + x.z*y.z + x.w*y.w;
      }
      Vf[tid] = a4;
    }
    float pv = (tid < N_ST) ? f[tid] * vin[tid] : 0.0f;
    red[tid] = pv;
    __syncthreads();
    for (int s2 = 512; s2 > 0; s2 >>= 1) {
      if (tid < s2) red[tid] += red[tid + s2];
      __syncthreads();
    }
    if (tid == 0) *fv = red[0];
  }
}

// ---------------------------------------------------------------------------
// TRSM: per column j (0..511 = Qux cols, 512 = qu):
//   forward  L w = b  -> Wt row j (and wv) ;  backward L^T y = w -> K (and k)
// Writes Wt (512x128 fp32) + bf16 split Wth/Wtl for the Vn MFMA GEMM.
// ---------------------------------------------------------------------------
__global__ __launch_bounds__(256) void trsm_kernel(
    const float* __restrict__ Lw,
    const float* __restrict__ invd,
    const float* __restrict__ Qm,
    const float* __restrict__ qv,
    float* __restrict__ Wt,
    ushort* __restrict__ Wth,
    ushort* __restrict__ Wtl,
    float* __restrict__ wv,
    float* __restrict__ kv,
    float* __restrict__ outK,
    float* __restrict__ outks)
{
  __shared__ float Lp[LTRI];
  __shared__ float di[128];
  const int tid = threadIdx.x;
  for (int idx = tid; idx < LTRI; idx += 256) Lp[idx] = Lw[idx];
  if (tid < 128) di[tid] = invd[tid];
  __syncthreads();

  const int wvid = tid >> 6, lane = tid & 63;
  const int j = blockIdx.x * 4 + wvid;
  if (j > N_ST) return;

  float b0, b1;
  if (j < N_ST) {
    b0 = Qm[(size_t)(N_ST + lane)*DIM + j];
    b1 = Qm[(size_t)(N_ST + 64 + lane)*DIM + j];
  } else {
    b0 = qv[N_ST + lane];
    b1 = qv[N_ST + 64 + lane];
  }

  float x0 = 0.0f, x1 = 0.0f;
  int uoff = 0;
  for (int u = 0; u < 128; u++) {
    float s = Lp[uoff + lane]*x0 + Lp[uoff + 64 + lane]*x1;
#pragma unroll
    for (int off = 32; off > 0; off >>= 1) s += __shfl_xor(s, off);
    float bu = (u < 64) ? __shfl(b0, u) : __shfl(b1, u - 64);
    float wu = (bu - s) * di[u];
    if (u < 64) { if (lane == u)      x0 = wu; }
    else        { if (lane == u - 64) x1 = wu; }
    uoff += u + 1;
  }
  if (j < N_ST) {
    size_t o = (size_t)j * N_CT;
    Wt[o + lane] = x0; Wt[o + 64 + lane] = x1;
    ushort h0 = f2bf(x0), h1 = f2bf(x1);
    Wth[o + lane] = h0;      Wtl[o + lane] = f2bf(x0 - bf2f(h0));
    Wth[o + 64 + lane] = h1; Wtl[o + 64 + lane] = f2bf(x1 - bf2f(h1));
  } else {
    wv[lane] = x0; wv[64 + lane] = x1;
  }

  const int toff0 = lane*(lane + 1)/2;
  const int toff1 = (64 + lane)*(65 + lane)/2;
  float y0 = 0.0f, y1 = 0.0f;
  for (int u = 127; u >= 0; u--) {
    float s = Lp[toff0 + u]*y0 + Lp[toff1 + u]*y1;
#pragma unroll
    for (int off = 32; off > 0; off >>= 1) s += __shfl_xor(s, off);
    float wu2 = (u < 64) ? __shfl(x0, u) : __shfl(x1, u - 64);
    float yu = (wu2 - s) * di[u];
    if (u < 64) { if (lane == u)      y0 = yu; }
    else        { if (lane == u - 64) y1 = yu; }
  }
  if (j < N_ST) {
    outK[(size_t)lane*N_ST + j]        = -y0;
    outK[(size_t)(64 + lane)*N_ST + j] = -y1;
  } else {
    kv[lane] = -y0; kv[64 + lane] = -y1;
    outks[lane] = -y0; outks[64 + lane] = -y1;
  }
}

// ---------------------------------------------------------------------------
// finish_aux (3 blocks x 256): blocks 0,1: vn = qx - Wt @ wv ; block 2: const
// ---------------------------------------------------------------------------
__global__ __launch_bounds__(256) void finish_aux(
    const float* __restrict__ Qm,
    const float* __restrict__ qv,
    const float* __restrict__ Wt,
    const float* __restrict__ wv,
    const float* __restrict__ kv,
    const float* __restrict__ Vf,
    const float* __restrict__ fv,
    const float* __restrict__ f,
    const float* __restrict__ constp,
    float* __restrict__ outv,
    float* __restrict__ outc,
    float* __restrict__ wsconst)
{
  const int b = blockIdx.x, tid = threadIdx.x;
  if (b < 2) {
    int i = b*256 + tid;
    const float4* wr = (const float4*)(Wt + (size_t)i * N_CT);
    const float4* w4 = (const float4*)wv;
    float acc = 0.0f;
    for (int u = 0; u < N_CT/4; u++) {
      float4 x = wr[u], y = w4[u];
      acc += x.x*y.x + x.y*y.y + x.z*y.z + x.w*y.w;
    }
    outv[i] = qv[i] - acc;
  } else {
    __shared__ float red[256];
    float pv = 0.0f;
    if (tid < 128) {
      float qk = 0.0f;
      for (int u = 0; u < 128; u++)
        qk += Qm[(size_t)(N_ST + tid)*DIM + N_ST + u] * kv[u];
      pv = kv[tid] * (0.5f*qk + qv[N_ST + tid]);
      float fa = 0.0f;
#pragma unroll
      for (int r = 0; r < 4; r++) { int jj = tid*4 + r; fa += f[jj] * Vf[jj]; }
      pv += 0.5f * fa;
    }
    red[tid] = pv;
    __syncthreads();
    for (int s2 = 128; s2 > 0; s2 >>= 1) {
      if (tid < s2) red[tid] += red[tid + s2];
      __syncthreads();
    }
    if (tid == 0) {
      float cn = constp[0] + red[0] + fv[0];
      outc[0] = cn;
      wsconst[0] = cn;
    }
  }
}

// ---------------------------------------------------------------------------
extern "C" void kernel_launch(void* const* d_in, const int* in_sizes, int n_in,
                              void* d_out, int out_size, void* d_ws, size_t ws_size,
                              hipStream_t stream)
{
  (void)in_sizes; (void)n_in; (void)out_size; (void)ws_size;
  const float* F  = (const float*)d_in[0];   // (512, 640)
  const float* f  = (const float*)d_in[1];   // (512,)
  const float* Cm = (const float*)d_in[2];   // (640, 640)
  const float* cv = (const float*)d_in[3];   // (640,)

  float* out   = (float*)d_out;
  float* outK  = out;                                        // T x 128 x 512
  float* outks = outK  + (size_t)T_H * N_CT * N_ST;          // T x 128
  float* outVs = outks + (size_t)T_H * N_CT;                 // T x 512 x 512
  float* outvs = outVs + (size_t)T_H * N_ST * N_ST;          // T x 512
  float* outcs = outvs + (size_t)T_H * N_ST;                 // T

  // workspace layout (float units, every array 256B-aligned)
  float* ws   = (float*)d_ws;
  float* FV   = ws;                          // 640*512
  float* Qm   = FV   + (size_t)DIM * N_ST;   // 640*640
  float* qv   = Qm   + (size_t)DIM * DIM;    // 640
  float* Lw   = qv   + DIM;                  // 8256
  float* invd = Lw   + LTRI;                 // 128
  float* Wt   = invd + 128;                  // 512*128
  float* wv   = Wt   + (size_t)N_ST * N_CT;  // 128
  float* kv   = wv   + 128;                  // 128
  float* Vf   = kv   + 128;                  // 512
  float* fv   = Vf   + N_ST;                 // (pad 64)
  float* cst  = fv   + 64;                   // (pad 64)
  ushort* FTh = (ushort*)(cst + 64);                 // 640*512
  ushort* FTl = FTh + (size_t)DIM * N_ST;            // 640*512
  ushort* Vh  = FTl + (size_t)DIM * N_ST;            // 512*512
  ushort* Vl  = Vh  + (size_t)N_ST * N_ST;           // 512*512
  ushort* FVh = Vl  + (size_t)N_ST * N_ST;           // 640*512
  ushort* FVl = FVh + (size_t)DIM * N_ST;            // 640*512
  ushort* Wth = FVl + (size_t)DIM * N_ST;            // 512*128
  ushort* Wtl = Wth + (size_t)N_ST * N_CT;           // 512*128

  hipMemsetAsync(cst, 0, sizeof(float), stream);

  // one-time conversions (cheap, per launch)
  convert_FT<<<dim3(DIM/32, N_ST/32), 256, 0, stream>>>(F, FTh, FTl);
  convert_V0<<<(N_ST*N_ST)/256, 256, 0, stream>>>(Cm, Vh, Vl);

  for (int s = 0; s < T_H; s++) {
    const float* Vin; int ldV; const float* vin;
    if (s == 0) { Vin = Cm; ldV = DIM; vin = cv; }
    else {
      Vin = outVs + (size_t)(T_H - s) * N_ST * N_ST; ldV = N_ST;
      vin = outvs + (size_t)(T_H - s) * N_ST;
    }
    const size_t slot = (size_t)(T_H - 1 - s);

    // FV = F^T V : A=FT (640xK), B=V rows (symmetry), split output for gemm2
    gemm_nt_mfma<<<dim3(DIM/64, N_ST/64), 256, 0, stream>>>(
        FTh, FTl, N_ST, Vh, Vl, N_ST, nullptr, 0, 1.0f,
        FV, N_ST, FVh, FVl, N_ST);
    // Q = C + FV F : A=FV, B=FT rows
    gemm_nt_mfma<<<dim3(DIM/64, DIM/64), 256, 0, stream>>>(
        FVh, FVl, N_ST, FTh, FTl, N_ST, Cm, DIM, 1.0f,
        Qm, DIM, nullptr, nullptr, N_ST);
    // Cholesky(Quu) + q + Vf + fv
    combo_kernel<<<3, 1024, 0, stream>>>(Qm, FV, F, f, cv, vin, Vin, ldV,
                                         qv, Vf, fv, Lw, invd);
    // Wt, wv, K, k
    trsm_kernel<<<129, 256, 0, stream>>>(Lw, invd, Qm, qv, Wt, Wth, Wtl,
                                         wv, kv,
                                         outK + slot * N_CT * N_ST,
                                         outks + slot * N_CT);
    // Vn = Qxx - Wt Wt^T : A=B=Wt rows, beta=-1, addend Qxx; split out -> V
    gemm_nt_mfma<<<dim3(N_ST/64, N_ST/64), 256, 0, stream>>>(
        Wth, Wtl, N_CT, Wth, Wtl, N_CT, Qm, DIM, -1.0f,
        outVs + slot * N_ST * N_ST, N_ST, Vh, Vl, N_CT);
    // vn, const
    finish_aux<<<3, 256, 0, stream>>>(Qm, qv, Wt, wv, kv, Vf, fv, f, cst,
                                      outvs + slot * N_ST,
                                      outcs + slot, cst);
  }
}